// Round 8
// baseline (3535.759 us; speedup 1.0000x reference)
//
#include <hip/hip_runtime.h>
#include <math.h>

// ---------------------------------------------------------------------------
// MACE layer, round 8 = round 7 with the workspace-overlap bug fixed.
// (Round 7 crashed: v_uph overlapped wT/row_st/cursor/elist; k_up overwrote
//  elist -> k_edge read garbage edge indices -> OOB -> abort.)
//
// Workspace layout (float offsets, non-overlapping):
//   acc    [N*256 f32]        @ 0         -> [0,        8388608)
//   s_uph  [N*64  ushort]     @ 8388608   -> [8388608,  9437184)
//   v_uph  [N*192 ushort]     @ 9437184   -> [9437184, 12582912)
//   wT     [25088 f32]        @ 12582912  -> [12582912,12608000)
//   row_st [32772 ints]       @ 12608000
//   cursor [32768 ints]       @ 12640772
//   elist  [262144 ints]      @ 12673540  -> ends 12935684
//   m_buf  [EC*256 ushort]    @ 12935684  (16B-aligned)
// 1-chunk total 186.0 MB; 2-chunk total 118.9 MB (proven ws >= 136 MB).
// ---------------------------------------------------------------------------

#define NN 32768
#define EE 262144
#define INV8 0.125f                      // 1/sqrt(64)
#define INV_SQRT8 0.35355339059327373f   // 1/sqrt(8)
#define INVZ 0.039528470752104741f       // 1/sqrt(64*10)
#define EPS_C 0.25f
#define RS2 0.70710678118654752f         // 1/sqrt(2)

__device__ __forceinline__ unsigned bfpair(float lo, float hi) {
  unsigned ul = __float_as_uint(lo);
  unsigned uh = __float_as_uint(hi);
  ul = (ul + 0x7FFFu + ((ul >> 16) & 1u)) >> 16;
  uh = (uh + 0x7FFFu + ((uh >> 16) & 1u)) >> 16;
  return ul | (uh << 16);
}
__device__ __forceinline__ unsigned short bf1(float x) {
  unsigned u = __float_as_uint(x);
  return (unsigned short)((u + 0x7FFFu + ((u >> 16) & 1u)) >> 16);
}
__device__ __forceinline__ float lo16(unsigned u) {
  return __uint_as_float(u << 16);
}
__device__ __forceinline__ float hi16(unsigned u) {
  return __uint_as_float(u & 0xFFFF0000u);
}

// W1T[j][r] (512) | W3T[j][k] (4096) | W4R[fb][k][p*8+j] (20480)
__global__ __launch_bounds__(256) void k_wt(
    const float* __restrict__ W1, const float* __restrict__ W3,
    const float* __restrict__ W4, float* __restrict__ dst) {
  int i = blockIdx.x * 256 + threadIdx.x;  // 25088 total
  if (i < 512) {
    dst[i] = W1[(i & 7) * 64 + (i >> 3)];           // W1T[j][r]
  } else if (i < 4608) {
    int i2 = i - 512;
    dst[i] = W3[(i2 & 63) * 64 + (i2 >> 6)];        // W3T[j][k]
  } else {
    int i4 = i - 4608;                               // fb*2560 + k*40 + p*8 + j
    int fb = i4 / 2560;
    int r = i4 - fb * 2560;
    int k = r / 40;
    int pj = r - k * 40;
    int p = pj >> 3, j = pj & 7;
    dst[i] = W4[k * 320 + p * 64 + fb * 8 + j];
  }
}

__global__ __launch_bounds__(256) void k_hist(const int* __restrict__ rcv,
                                              int* __restrict__ cnt) {
  int e = blockIdx.x * 256 + threadIdx.x;
  atomicAdd(&cnt[rcv[e]], 1);
}

__global__ __launch_bounds__(1024) void k_scan(const int* __restrict__ cnt,
                                               int* __restrict__ row_start,
                                               int* __restrict__ cursor) {
  __shared__ int tot[1024];
  int t = threadIdx.x;
  int base = t * 32;
  int local[32];
  int s = 0;
#pragma unroll
  for (int i = 0; i < 32; ++i) { local[i] = s; s += cnt[base + i]; }
  tot[t] = s;
  __syncthreads();
  for (int off = 1; off < 1024; off <<= 1) {
    int v = (t >= off) ? tot[t - off] : 0;
    __syncthreads();
    tot[t] += v;
    __syncthreads();
  }
  int prefix = (t == 0) ? 0 : tot[t - 1];
#pragma unroll
  for (int i = 0; i < 32; ++i) {
    int v = prefix + local[i];
    row_start[base + i] = v;
    cursor[base + i] = v;
  }
  if (t == 1023) row_start[NN] = prefix + s;
}

__global__ __launch_bounds__(256) void k_fill(const int* __restrict__ rcv,
                                              int* __restrict__ cursor,
                                              int* __restrict__ elist) {
  int e = blockIdx.x * 256 + threadIdx.x;
  int pos = atomicAdd(&cursor[rcv[e]], 1);
  elist[pos] = e;
}

// linear_up -> bf16 outputs. lane g = output channel; weights coalesced.
__global__ __launch_bounds__(256) void k_up(
    const float* __restrict__ nf,
    const float* __restrict__ Wups, const float* __restrict__ Wupv,
    unsigned short* __restrict__ s_uph, unsigned short* __restrict__ v_uph) {
  int g = threadIdx.x & 63;
  int n0 = (blockIdx.x * 4 + (threadIdx.x >> 6)) * 4;
  float su[4] = {0.f, 0.f, 0.f, 0.f};
  float vu[4][3] = {{0,0,0},{0,0,0},{0,0,0},{0,0,0}};
  for (int fq = 0; fq < 16; ++fq) {
    int f = fq * 4;
    float ws0 = Wups[(f + 0) * 64 + g], ws1 = Wups[(f + 1) * 64 + g];
    float ws2 = Wups[(f + 2) * 64 + g], ws3 = Wups[(f + 3) * 64 + g];
    float wv0 = Wupv[(f + 0) * 64 + g], wv1 = Wupv[(f + 1) * 64 + g];
    float wv2 = Wupv[(f + 2) * 64 + g], wv3 = Wupv[(f + 3) * 64 + g];
#pragma unroll
    for (int i = 0; i < 4; ++i) {
      const float* row = nf + (size_t)(n0 + i) * 256;
      float4 s4 = *(const float4*)(row + f);
      const float4* vr = (const float4*)(row + 64 + fq * 12);
      float4 va = vr[0], vb = vr[1], vc = vr[2];
      su[i]    += s4.x * ws0 + s4.y * ws1 + s4.z * ws2 + s4.w * ws3;
      vu[i][0] += va.x * wv0 + va.w * wv1 + vb.z * wv2 + vc.y * wv3;
      vu[i][1] += va.y * wv0 + vb.x * wv1 + vb.w * wv2 + vc.z * wv3;
      vu[i][2] += va.z * wv0 + vb.y * wv1 + vc.x * wv2 + vc.w * wv3;
    }
  }
#pragma unroll
  for (int i = 0; i < 4; ++i) {
    int n = n0 + i;
    s_uph[n * 64 + g] = bf1(su[i] * INV8);
    v_uph[(n * 3 + 0) * 64 + g] = bf1(vu[i][0] * INV8);
    v_uph[(n * 3 + 1) * 64 + g] = bf1(vu[i][1] * INV8);
    v_uph[(n * 3 + 2) * 64 + g] = bf1(vu[i][2] * INV8);
  }
}

__device__ __forceinline__ float silu_f(float x) {
  return x / (1.0f + __expf(-x));
}

// thread-per-edge in CSR order. h1 regs -> h2 packed-bf16 LDS (16 KB) ->
// h3 regs -> layer4+TP -> bf16 message store. Weights via uniform s_load.
__global__ __launch_bounds__(128) void k_edge(
    const float* __restrict__ vecs, const float* __restrict__ re,
    const float* __restrict__ W1T, const float* __restrict__ W2,
    const float* __restrict__ W3T, const float* __restrict__ W4R,
    const unsigned short* __restrict__ s_uph,
    const unsigned short* __restrict__ v_uph,
    const int* __restrict__ snd, const int* __restrict__ elist,
    int e0, unsigned short* __restrict__ m_buf) {
  __shared__ unsigned lhu[128 * 32];  // 16 KB packed bf16 h2
  int t = threadIdx.x;
  int ip = blockIdx.x * 128 + t;       // chunk-local CSR position
  int e = elist[e0 + ip];
  unsigned* hbu = lhu + t * 32;

  // hoist edge geometry + gather indices
  float ex = vecs[(size_t)e * 3 + 0];
  float ey = vecs[(size_t)e * 3 + 1];
  float ez = vecs[(size_t)e * 3 + 2];
  int se = snd[e];

  float r8[8];
  {
    const float4* rp = (const float4*)(re + (size_t)e * 8);
    float4 ra = rp[0], rb = rp[1];
    r8[0] = ra.x; r8[1] = ra.y; r8[2] = ra.z; r8[3] = ra.w;
    r8[4] = rb.x; r8[5] = rb.y; r8[6] = rb.z; r8[7] = rb.w;
  }

  // layer 1 -> h1 registers
  float h1[64];
#pragma unroll
  for (int j = 0; j < 64; ++j) {
    const float* w = W1T + j * 8;      // uniform -> s_load
    float a = 0.f;
#pragma unroll
    for (int r = 0; r < 8; ++r) a += r8[r] * w[r];
    h1[j] = silu_f(a * INV_SQRT8);
  }

  // layer 2: h1 regs -> h2 LDS (bf16 pairs; pair p at word ((p+t)&31): 2-way)
#pragma unroll 1
  for (int jb = 0; jb < 8; ++jb) {
    float acc[8] = {0, 0, 0, 0, 0, 0, 0, 0};
#pragma unroll
    for (int k = 0; k < 64; ++k) {
      const float* wr = W2 + k * 64 + jb * 8;  // uniform -> s_load_dwordx8
      float hk = h1[k];
#pragma unroll
      for (int jj = 0; jj < 8; ++jj) acc[jj] += hk * wr[jj];
    }
#pragma unroll
    for (int q = 0; q < 4; ++q)
      hbu[((jb * 4 + q) + t) & 31] =
          bfpair(silu_f(acc[2 * q] * INV8), silu_f(acc[2 * q + 1] * INV8));
  }

  // layer 3: h2 LDS -> h3 regs (8 chains, 16-channel cache per k16 block)
  float h3[64];
#pragma unroll
  for (int g8 = 0; g8 < 8; ++g8) {
    float a8[8] = {0, 0, 0, 0, 0, 0, 0, 0};
#pragma unroll 1
    for (int k16 = 0; k16 < 4; ++k16) {
      float hc[16];
#pragma unroll
      for (int q = 0; q < 8; ++q) {
        unsigned u = hbu[((k16 * 8 + q) + t) & 31];
        hc[2 * q] = lo16(u);
        hc[2 * q + 1] = hi16(u);
      }
#pragma unroll
      for (int jj = 0; jj < 8; ++jj) {
        const float* w = W3T + (g8 * 8 + jj) * 64 + k16 * 16;  // uniform
        float a = 0.f;
#pragma unroll
        for (int k = 0; k < 16; ++k) a += hc[k] * w[k];
        a8[jj] += a;
      }
    }
#pragma unroll
    for (int jj = 0; jj < 8; ++jj)
      h3[g8 * 8 + jj] = silu_f(a8[jj] * INV8);
  }

  float rn = 1.0f / (sqrtf(ex * ex + ey * ey + ez * ez) + 1e-9f);
  float Yx = ex * rn, Yy = ey * rn, Yz = ez * rn;
  const unsigned short* sr = s_uph + (size_t)se * 64;
  const unsigned short* vr = v_uph + (size_t)se * 192;
  unsigned short* mrow = m_buf + (size_t)ip * 256;
  const float C = EPS_C * INV8;  // fold layer4 1/sqrt(H) + EPS into store

  // layer 4: W4R[fb] contiguous 2560-float run, consumed sequentially.
#pragma unroll 1
  for (int fb = 0; fb < 8; ++fb) {
    const float* base = W4R + fb * 2560;
    float w[5][8];
#pragma unroll
    for (int p = 0; p < 5; ++p)
#pragma unroll
      for (int j = 0; j < 8; ++j) w[p][j] = 0.0f;
#pragma unroll
    for (int k = 0; k < 64; ++k) {
      const float* wr = base + k * 40;  // uniform, contiguous -> wide s_load
      float hk = h3[k];
#pragma unroll
      for (int p = 0; p < 5; ++p)
#pragma unroll
        for (int j = 0; j < 8; ++j) w[p][j] += hk * wr[p * 8 + j];
    }
    uint4 S = *(const uint4*)(sr + fb * 8);
    uint4 X = *(const uint4*)(vr + fb * 8);
    uint4 Yv = *(const uint4*)(vr + 64 + fb * 8);
    uint4 Zv = *(const uint4*)(vr + 128 + fb * 8);
    float ssv[8] = {lo16(S.x), hi16(S.x), lo16(S.y), hi16(S.y),
                    lo16(S.z), hi16(S.z), lo16(S.w), hi16(S.w)};
    float vxv[8] = {lo16(X.x), hi16(X.x), lo16(X.y), hi16(X.y),
                    lo16(X.z), hi16(X.z), lo16(X.w), hi16(X.w)};
    float vyv[8] = {lo16(Yv.x), hi16(Yv.x), lo16(Yv.y), hi16(Yv.y),
                    lo16(Yv.z), hi16(Yv.z), lo16(Yv.w), hi16(Yv.w)};
    float vzv[8] = {lo16(Zv.x), hi16(Zv.x), lo16(Zv.y), hi16(Zv.y),
                    lo16(Zv.z), hi16(Zv.z), lo16(Zv.w), hi16(Zv.w)};
    float ms[8], mx[8], my[8], mz[8];
#pragma unroll
    for (int j = 0; j < 8; ++j) {
      float vvx = vxv[j], vvy = vyv[j], vvz = vzv[j];
      float dt = vvx * Yx + vvy * Yy + vvz * Yz;
      float cx = vvy * Yz - vvz * Yy;
      float cy = vvz * Yx - vvx * Yz;
      float cz = vvx * Yy - vvy * Yx;
      ms[j] = C * (w[0][j] * ssv[j] + w[3][j] * dt);
      mx[j] = C * (w[1][j] * Yx + w[2][j] * vvx + w[4][j] * (cx * RS2));
      my[j] = C * (w[1][j] * Yy + w[2][j] * vvy + w[4][j] * (cy * RS2));
      mz[j] = C * (w[1][j] * Yz + w[2][j] * vvz + w[4][j] * (cz * RS2));
    }
    uint4 pk;
    pk.x = bfpair(ms[0], ms[1]); pk.y = bfpair(ms[2], ms[3]);
    pk.z = bfpair(ms[4], ms[5]); pk.w = bfpair(ms[6], ms[7]);
    *(uint4*)(mrow + fb * 8) = pk;
    pk.x = bfpair(mx[0], mx[1]); pk.y = bfpair(mx[2], mx[3]);
    pk.z = bfpair(mx[4], mx[5]); pk.w = bfpair(mx[6], mx[7]);
    *(uint4*)(mrow + 64 + fb * 8) = pk;
    pk.x = bfpair(my[0], my[1]); pk.y = bfpair(my[2], my[3]);
    pk.z = bfpair(my[4], my[5]); pk.w = bfpair(my[6], my[7]);
    *(uint4*)(mrow + 128 + fb * 8) = pk;
    pk.x = bfpair(mz[0], mz[1]); pk.y = bfpair(mz[2], mz[3]);
    pk.z = bfpair(mz[4], mz[5]); pk.w = bfpair(mz[6], mz[7]);
    *(uint4*)(mrow + 192 + fb * 8) = pk;
  }
}

// one wave per node; contiguous clipped CSR range [lo,hi) of this chunk.
__global__ __launch_bounds__(256) void k_gather(
    const unsigned short* __restrict__ m_buf,
    const int* __restrict__ row_start,
    float* __restrict__ acc, int e0, int e1) {
  int g = threadIdx.x & 63;
  int wv = threadIdx.x >> 6;
  int n = blockIdx.x * 4 + wv;
  int beg = row_start[n], end = row_start[n + 1];
  int lo = beg > e0 ? beg : e0;
  int hi = end < e1 ? end : e1;
  if (lo >= hi) return;
  float4 a = make_float4(0.f, 0.f, 0.f, 0.f);
  for (int i = lo; i < hi; ++i) {
    uint2 m = *(const uint2*)(m_buf + (size_t)(i - e0) * 256 + g * 4);
    a.x += lo16(m.x);
    a.y += hi16(m.x);
    a.z += lo16(m.y);
    a.w += hi16(m.y);
  }
  float* dst = acc + (size_t)n * 256 + g * 4;
  float4 p = *(const float4*)dst;  // serialized chunks: RMW is safe
  *(float4*)dst = make_float4(a.x + p.x, a.y + p.y, a.z + p.z, a.w + p.w);
}

__global__ __launch_bounds__(256) void k_post(
    const float* __restrict__ nf, const float* __restrict__ acc,
    const float* __restrict__ Wdns, const float* __restrict__ Wdnv,
    const float* __restrict__ Wsks, const float* __restrict__ Wskv,
    const float* __restrict__ Wsc,
    const float* __restrict__ Wpss, const float* __restrict__ Wpsv,
    const float* __restrict__ Wout, const int* __restrict__ species,
    float* __restrict__ out) {
  __shared__ __align__(16) float xch[4][4][4][68];
  int g = threadIdx.x & 63;
  int wv = threadIdx.x >> 6;
  int n0 = (blockIdx.x * 4 + wv) * 4;
  int spec[4];
#pragma unroll
  for (int i = 0; i < 4; ++i) spec[i] = species[n0 + i];
  float s3[4] = {0, 0, 0, 0};
  float v3[4][3] = {{0,0,0},{0,0,0},{0,0,0},{0,0,0}};
  float sks[4] = {0, 0, 0, 0};
  float skv[4][3] = {{0,0,0},{0,0,0},{0,0,0},{0,0,0}};
  for (int fq = 0; fq < 16; ++fq) {
    int f = fq * 4;
    float d0 = Wdns[(f + 0) * 64 + g], d1 = Wdns[(f + 1) * 64 + g];
    float d2 = Wdns[(f + 2) * 64 + g], d3 = Wdns[(f + 3) * 64 + g];
    float e0 = Wdnv[(f + 0) * 64 + g], e1 = Wdnv[(f + 1) * 64 + g];
    float e2 = Wdnv[(f + 2) * 64 + g], e3 = Wdnv[(f + 3) * 64 + g];
#pragma unroll
    for (int i = 0; i < 4; ++i) {
      int n = n0 + i;
      const float* arow = acc + (size_t)n * 256;
      float4 sa = *(const float4*)(arow + f);
      float4 vx = *(const float4*)(arow + 64 + f);
      float4 vy = *(const float4*)(arow + 128 + f);
      float4 vz = *(const float4*)(arow + 192 + f);
      s3[i]    += sa.x * d0 + sa.y * d1 + sa.z * d2 + sa.w * d3;
      v3[i][0] += vx.x * e0 + vx.y * e1 + vx.z * e2 + vx.w * e3;
      v3[i][1] += vy.x * e0 + vy.y * e1 + vy.z * e2 + vy.w * e3;
      v3[i][2] += vz.x * e0 + vz.y * e1 + vz.z * e2 + vz.w * e3;
      const float* ksb = Wsks + spec[i] * 4096 + f * 64 + g;
      const float* kvb = Wskv + spec[i] * 4096 + f * 64 + g;
      float k0 = ksb[0], k1 = ksb[64], k2 = ksb[128], k3 = ksb[192];
      float q0 = kvb[0], q1 = kvb[64], q2 = kvb[128], q3 = kvb[192];
      const float* row = nf + (size_t)n * 256;
      float4 s04 = *(const float4*)(row + f);
      const float4* vr = (const float4*)(row + 64 + fq * 12);
      float4 va = vr[0], vb = vr[1], vc = vr[2];
      sks[i]    += s04.x * k0 + s04.y * k1 + s04.z * k2 + s04.w * k3;
      skv[i][0] += va.x * q0 + va.w * q1 + vb.z * q2 + vc.y * q3;
      skv[i][1] += va.y * q0 + vb.x * q1 + vb.w * q2 + vc.z * q3;
      skv[i][2] += va.z * q0 + vb.y * q1 + vc.x * q2 + vc.w * q3;
    }
  }
#pragma unroll
  for (int i = 0; i < 4; ++i) {
    float s = s3[i] * INV8;
    float vx = v3[i][0] * INV8, vy = v3[i][1] * INV8, vz = v3[i][2] * INV8;
    float vn2 = vx * vx + vy * vy + vz * vz;
    const float* wz = Wsc + spec[i] * 576 + g;
    float w0 = wz[0], w1 = wz[64], w2 = wz[128], w3 = wz[192], w4 = wz[256];
    float w5 = wz[320], w6 = wz[384], w7 = wz[448], w8 = wz[512];
    float s_o = w0 * s + w1 * s * s + w2 * vn2 + w3 * s * s * s + w4 * s * vn2;
    float vcm = w5 + w6 * s + w7 * s * s + w8 * vn2;
    xch[wv][i][0][g] = s_o;
    xch[wv][i][1][g] = vcm * vx;
    xch[wv][i][2][g] = vcm * vy;
    xch[wv][i][3][g] = vcm * vz;
  }
  __syncthreads();
  float s4[4] = {0, 0, 0, 0};
  float v4[4][3] = {{0,0,0},{0,0,0},{0,0,0},{0,0,0}};
  for (int fq = 0; fq < 16; ++fq) {
    int f = fq * 4;
    float p0 = Wpss[(f + 0) * 64 + g], p1 = Wpss[(f + 1) * 64 + g];
    float p2 = Wpss[(f + 2) * 64 + g], p3 = Wpss[(f + 3) * 64 + g];
    float q0 = Wpsv[(f + 0) * 64 + g], q1 = Wpsv[(f + 1) * 64 + g];
    float q2 = Wpsv[(f + 2) * 64 + g], q3 = Wpsv[(f + 3) * 64 + g];
#pragma unroll
    for (int i = 0; i < 4; ++i) {
      float4 so = *(const float4*)(&xch[wv][i][0][f]);
      float4 u0 = *(const float4*)(&xch[wv][i][1][f]);
      float4 u1 = *(const float4*)(&xch[wv][i][2][f]);
      float4 u2 = *(const float4*)(&xch[wv][i][3][f]);
      s4[i]    += so.x * p0 + so.y * p1 + so.z * p2 + so.w * p3;
      v4[i][0] += u0.x * q0 + u0.y * q1 + u0.z * q2 + u0.w * q3;
      v4[i][1] += u1.x * q0 + u1.y * q1 + u1.z * q2 + u1.w * q3;
      v4[i][2] += u2.x * q0 + u2.y * q1 + u2.z * q2 + u2.w * q3;
    }
  }
  float wo = Wout[g];
#pragma unroll
  for (int i = 0; i < 4; ++i) {
    int n = n0 + i;
    float sf = s4[i] * INV8 + sks[i] * INVZ;
    float fx = v4[i][0] * INV8 + skv[i][0] * INVZ;
    float fy = v4[i][1] * INV8 + skv[i][1] * INVZ;
    float fz = v4[i][2] * INV8 + skv[i][2] * INVZ;
    float* orow = out + NN + (size_t)n * 256;
    orow[g] = sf;
    orow[64 + g * 3 + 0] = fx;
    orow[64 + g * 3 + 1] = fy;
    orow[64 + g * 3 + 2] = fz;
    float tsum = sf * wo;
#pragma unroll
    for (int off = 32; off > 0; off >>= 1) tsum += __shfl_down(tsum, off);
    if (g == 0) out[n] = tsum * INV8;
  }
}

extern "C" void kernel_launch(void* const* d_in, const int* in_sizes, int n_in,
                              void* d_out, int out_size, void* d_ws, size_t ws_size,
                              hipStream_t stream) {
  (void)in_sizes; (void)n_in; (void)out_size;
  const float* vecs = (const float*)d_in[0];
  const float* nf   = (const float*)d_in[1];
  const float* re   = (const float*)d_in[2];
  const float* Wsks = (const float*)d_in[3];
  const float* Wskv = (const float*)d_in[4];
  const float* Wups = (const float*)d_in[5];
  const float* Wupv = (const float*)d_in[6];
  const float* W1   = (const float*)d_in[7];
  const float* W2   = (const float*)d_in[8];
  const float* W3   = (const float*)d_in[9];
  const float* W4   = (const float*)d_in[10];
  const float* Wdns = (const float*)d_in[11];
  const float* Wdnv = (const float*)d_in[12];
  const float* Wsc  = (const float*)d_in[13];
  const float* Wpss = (const float*)d_in[14];
  const float* Wpsv = (const float*)d_in[15];
  const float* Wout = (const float*)d_in[16];
  const int* species = (const int*)d_in[17];
  const int* snd     = (const int*)d_in[18];
  const int* rcv     = (const int*)d_in[19];

  float* ws = (float*)d_ws;
  float* acc = ws;                                         // [0, 8388608)
  unsigned short* s_uph = (unsigned short*)(ws + 8388608); // N*64 us
  unsigned short* v_uph = (unsigned short*)(ws + 9437184); // N*192 us
  float* wT    = ws + 12582912;                            // 25088
  int* row_st  = (int*)(ws + 12608000);                    // 32769 (+pad)
  int* cursor  = (int*)(ws + 12640772);                    // 32768
  int* elist   = (int*)(ws + 12673540);                    // 262144
  unsigned short* m_buf = (unsigned short*)(ws + 12935684);

  float* W1T = wT;
  float* W3T = wT + 512;
  float* W4R = wT + 4608;

  // single-chunk needs (12935684 + 262144*128) floats = 186.0 MB
  const size_t need1 = ((size_t)12935684 + (size_t)262144 * 128) * 4;
  const int nchunk = (ws_size >= need1) ? 1 : 2;
  const int ECd = EE / nchunk;

  hipMemsetAsync(cursor, 0, NN * sizeof(int), stream);
  hipMemsetAsync(acc, 0, (size_t)NN * 256 * sizeof(float), stream);
  k_wt<<<98, 256, 0, stream>>>(W1, W3, W4, wT);
  k_hist<<<EE / 256, 256, 0, stream>>>(rcv, cursor);
  k_scan<<<1, 1024, 0, stream>>>(cursor, row_st, cursor);
  k_fill<<<EE / 256, 256, 0, stream>>>(rcv, cursor, elist);
  k_up<<<2048, 256, 0, stream>>>(nf, Wups, Wupv, s_uph, v_uph);
  for (int c = 0; c < nchunk; ++c) {
    k_edge<<<ECd / 128, 128, 0, stream>>>(vecs, re, W1T, W2, W3T, W4R,
                                          s_uph, v_uph, snd, elist,
                                          c * ECd, m_buf);
    k_gather<<<NN / 4, 256, 0, stream>>>(m_buf, row_st, acc,
                                         c * ECd, (c + 1) * ECd);
  }
  k_post<<<2048, 256, 0, stream>>>(nf, acc, Wdns, Wdnv, Wsks, Wskv, Wsc,
                                   Wpss, Wpsv, Wout, species, (float*)d_out);
}

// Round 9
// 1144.340 us; speedup vs baseline: 3.0898x; 3.0898x over previous
//
#include <hip/hip_runtime.h>
#include <math.h>

// ---------------------------------------------------------------------------
// MACE layer, round 9.
//  - k_edge internals reverted to round 6 (f32 sender tables, f32 swizzled
//    LDS h2, bf16 messages): round 8's bf16-everything doubled VALU work,
//    cut waves/SIMD (144 VGPR), halved memory parallelism -> 4.6x regression.
//  - NEW: edges processed in SENDER-sorted order (selist). A wave's 64 edges
//    share ~8 sender rows -> gather fetch ~8x lower, L1-resident. k_gather
//    reads full 1KB-coalesced message rows anyway, so it only needs the
//    pos_s[e] indirection (+1 int/edge) with a chunk-range guard.
//
// Workspace layout (float offsets, non-overlapping):
//   s_up    [N*64  f32]   @ 0
//   v_up    [N*192 f32]   @ 2097152
//   acc     [N*256 f32]   @ 8388608
//   wT      [25088 f32]   @ 16777216   (W1T 512 | W3T 4096 | W4R 20480)
//   row_st_r[32772 ints]  @ 16802304
//   row_st_s[32772 ints]  @ 16835076
//   cursor_r[32768 ints]  @ 16867848   (cursor_r+cursor_s contiguous memset)
//   cursor_s[32768 ints]  @ 16900616
//   elist_r [262144 ints] @ 16933384
//   selist  [262144 ints] @ 17195528
//   pos_s   [262144 ints] @ 17457672
//   m_buf   [EC*256 us]   @ 17719816   (bf16, 2 chunks)  -> total ~138 MB
// ---------------------------------------------------------------------------

#define NN 32768
#define EE 262144
#define EC 131072                        // edges per chunk (2 chunks)
#define INV8 0.125f                      // 1/sqrt(64)
#define INV_SQRT8 0.35355339059327373f   // 1/sqrt(8)
#define INVZ 0.039528470752104741f       // 1/sqrt(64*10)
#define EPS_C 0.25f
#define RS2 0.70710678118654752f         // 1/sqrt(2)

__device__ __forceinline__ unsigned bfpair(float lo, float hi) {
  unsigned ul = __float_as_uint(lo);
  unsigned uh = __float_as_uint(hi);
  ul = (ul + 0x7FFFu + ((ul >> 16) & 1u)) >> 16;
  uh = (uh + 0x7FFFu + ((uh >> 16) & 1u)) >> 16;
  return ul | (uh << 16);
}
__device__ __forceinline__ float lo16(unsigned u) {
  return __uint_as_float(u << 16);
}
__device__ __forceinline__ float hi16(unsigned u) {
  return __uint_as_float(u & 0xFFFF0000u);
}

// W1T[j][r] (512) | W3T[j][k] (4096) | W4R[fb][k][p*8+j] (20480)
__global__ __launch_bounds__(256) void k_wt(
    const float* __restrict__ W1, const float* __restrict__ W3,
    const float* __restrict__ W4, float* __restrict__ dst) {
  int i = blockIdx.x * 256 + threadIdx.x;  // 25088 total
  if (i < 512) {
    dst[i] = W1[(i & 7) * 64 + (i >> 3)];           // W1T[j][r]
  } else if (i < 4608) {
    int i2 = i - 512;
    dst[i] = W3[(i2 & 63) * 64 + (i2 >> 6)];        // W3T[j][k]
  } else {
    int i4 = i - 4608;                               // fb*2560 + k*40 + p*8 + j
    int fb = i4 / 2560;
    int r = i4 - fb * 2560;
    int k = r / 40;
    int pj = r - k * 40;
    int p = pj >> 3, j = pj & 7;
    dst[i] = W4[k * 320 + p * 64 + fb * 8 + j];
  }
}

__global__ __launch_bounds__(256) void k_hist(const int* __restrict__ idx,
                                              int* __restrict__ cnt) {
  int e = blockIdx.x * 256 + threadIdx.x;
  atomicAdd(&cnt[idx[e]], 1);
}

__global__ __launch_bounds__(1024) void k_scan(const int* __restrict__ cnt,
                                               int* __restrict__ row_start,
                                               int* __restrict__ cursor) {
  __shared__ int tot[1024];
  int t = threadIdx.x;
  int base = t * 32;
  int local[32];
  int s = 0;
#pragma unroll
  for (int i = 0; i < 32; ++i) { local[i] = s; s += cnt[base + i]; }
  tot[t] = s;
  __syncthreads();
  for (int off = 1; off < 1024; off <<= 1) {
    int v = (t >= off) ? tot[t - off] : 0;
    __syncthreads();
    tot[t] += v;
    __syncthreads();
  }
  int prefix = (t == 0) ? 0 : tot[t - 1];
#pragma unroll
  for (int i = 0; i < 32; ++i) {
    int v = prefix + local[i];
    row_start[base + i] = v;
    cursor[base + i] = v;
  }
  if (t == 1023) row_start[NN] = prefix + s;
}

__global__ __launch_bounds__(256) void k_fill(const int* __restrict__ idx,
                                              int* __restrict__ cursor,
                                              int* __restrict__ elist) {
  int e = blockIdx.x * 256 + threadIdx.x;
  int pos = atomicAdd(&cursor[idx[e]], 1);
  elist[pos] = e;
}

// sender ordering: selist[pos] = e (for k_edge) and pos_s[e] = pos (for gather)
__global__ __launch_bounds__(256) void k_fill_pos(const int* __restrict__ snd,
                                                  int* __restrict__ cursor,
                                                  int* __restrict__ selist,
                                                  int* __restrict__ pos_s) {
  int e = blockIdx.x * 256 + threadIdx.x;
  int pos = atomicAdd(&cursor[snd[e]], 1);
  selist[pos] = e;
  pos_s[e] = pos;
}

// linear_up: lane g = output channel; weights original layout -> coalesced.
__global__ __launch_bounds__(256) void k_up(
    const float* __restrict__ nf,
    const float* __restrict__ Wups, const float* __restrict__ Wupv,
    float* __restrict__ s_up, float* __restrict__ v_up) {
  int g = threadIdx.x & 63;
  int n0 = (blockIdx.x * 4 + (threadIdx.x >> 6)) * 4;
  float su[4] = {0.f, 0.f, 0.f, 0.f};
  float vu[4][3] = {{0,0,0},{0,0,0},{0,0,0},{0,0,0}};
  for (int fq = 0; fq < 16; ++fq) {
    int f = fq * 4;
    float ws0 = Wups[(f + 0) * 64 + g], ws1 = Wups[(f + 1) * 64 + g];
    float ws2 = Wups[(f + 2) * 64 + g], ws3 = Wups[(f + 3) * 64 + g];
    float wv0 = Wupv[(f + 0) * 64 + g], wv1 = Wupv[(f + 1) * 64 + g];
    float wv2 = Wupv[(f + 2) * 64 + g], wv3 = Wupv[(f + 3) * 64 + g];
#pragma unroll
    for (int i = 0; i < 4; ++i) {
      const float* row = nf + (size_t)(n0 + i) * 256;
      float4 s4 = *(const float4*)(row + f);
      const float4* vr = (const float4*)(row + 64 + fq * 12);
      float4 va = vr[0], vb = vr[1], vc = vr[2];
      su[i]    += s4.x * ws0 + s4.y * ws1 + s4.z * ws2 + s4.w * ws3;
      vu[i][0] += va.x * wv0 + va.w * wv1 + vb.z * wv2 + vc.y * wv3;
      vu[i][1] += va.y * wv0 + vb.x * wv1 + vb.w * wv2 + vc.z * wv3;
      vu[i][2] += va.z * wv0 + vb.y * wv1 + vc.x * wv2 + vc.w * wv3;
    }
  }
#pragma unroll
  for (int i = 0; i < 4; ++i) {
    int n = n0 + i;
    s_up[n * 64 + g] = su[i] * INV8;
    v_up[(n * 3 + 0) * 64 + g] = vu[i][0] * INV8;
    v_up[(n * 3 + 1) * 64 + g] = vu[i][1] * INV8;
    v_up[(n * 3 + 2) * 64 + g] = vu[i][2] * INV8;
  }
}

__device__ __forceinline__ float silu_f(float x) {
  return x / (1.0f + __expf(-x));
}

// thread-per-edge in SENDER order. h1 regs -> h2 LDS (f32, swizzled) ->
// h3 regs -> layer4+TP -> bf16 message store at sender-order position.
__global__ __launch_bounds__(128) void k_edge(
    const float* __restrict__ vecs, const float* __restrict__ re,
    const float* __restrict__ W1T, const float* __restrict__ W2,
    const float* __restrict__ W3T, const float* __restrict__ W4R,
    const float* __restrict__ s_up, const float* __restrict__ v_up,
    const int* __restrict__ snd, const int* __restrict__ selist,
    int e0, unsigned short* __restrict__ m_buf) {
  __shared__ float lh[128 * 64];  // 32 KB
  int t = threadIdx.x;
  int ip = blockIdx.x * 128 + t;       // chunk-local sender-order position
  int e = selist[e0 + ip];
  float* hb = lh + t * 64;

  // hoist edge geometry + gather indices
  float ex = vecs[(size_t)e * 3 + 0];
  float ey = vecs[(size_t)e * 3 + 1];
  float ez = vecs[(size_t)e * 3 + 2];
  int se = snd[e];

  float r8[8];
  {
    const float4* rp = (const float4*)(re + (size_t)e * 8);
    float4 ra = rp[0], rb = rp[1];
    r8[0] = ra.x; r8[1] = ra.y; r8[2] = ra.z; r8[3] = ra.w;
    r8[4] = rb.x; r8[5] = rb.y; r8[6] = rb.z; r8[7] = rb.w;
  }

  // layer 1 -> h1 registers
  float h1[64];
#pragma unroll
  for (int j = 0; j < 64; ++j) {
    const float* w = W1T + j * 8;      // uniform -> s_load
    float a = 0.f;
#pragma unroll
    for (int r = 0; r < 8; ++r) a += r8[r] * w[r];
    h1[j] = silu_f(a * INV_SQRT8);
  }

  // layer 2: h1 regs -> h2 LDS. jb-blocked 8 independent chains; W2 original
  // layout -> one uniform dwordx8 per (k,jb). Swizzle (j+t)&63: 2-way = free.
#pragma unroll 1
  for (int jb = 0; jb < 8; ++jb) {
    float acc[8] = {0, 0, 0, 0, 0, 0, 0, 0};
#pragma unroll
    for (int k = 0; k < 64; ++k) {
      const float* wr = W2 + k * 64 + jb * 8;  // uniform -> s_load_dwordx8
      float hk = h1[k];
#pragma unroll
      for (int jj = 0; jj < 8; ++jj) acc[jj] += hk * wr[jj];
    }
#pragma unroll
    for (int jj = 0; jj < 8; ++jj)
      hb[(jb * 8 + jj + t) & 63] = silu_f(acc[jj] * INV8);
  }

  // layer 3: h2 LDS -> h3 regs (8 chains, 16-value LDS cache)
  float h3[64];
#pragma unroll
  for (int g8 = 0; g8 < 8; ++g8) {
    float a8[8] = {0, 0, 0, 0, 0, 0, 0, 0};
#pragma unroll 1
    for (int k16 = 0; k16 < 4; ++k16) {
      float hc[16];
#pragma unroll
      for (int k = 0; k < 16; ++k) hc[k] = hb[(k16 * 16 + k + t) & 63];
#pragma unroll
      for (int jj = 0; jj < 8; ++jj) {
        const float* w = W3T + (g8 * 8 + jj) * 64 + k16 * 16;  // uniform
        float a = 0.f;
#pragma unroll
        for (int k = 0; k < 16; ++k) a += hc[k] * w[k];
        a8[jj] += a;
      }
    }
#pragma unroll
    for (int jj = 0; jj < 8; ++jj)
      h3[g8 * 8 + jj] = silu_f(a8[jj] * INV8);
  }

  float rn = 1.0f / (sqrtf(ex * ex + ey * ey + ez * ez) + 1e-9f);
  float Yx = ex * rn, Yy = ey * rn, Yz = ez * rn;
  const float* srow = s_up + (size_t)se * 64;   // shared by ~8 nearby threads
  const float* vrow = v_up + (size_t)se * 192;  // -> L1 hits
  unsigned short* mrow = m_buf + (size_t)ip * 256;
  const float C = EPS_C * INV8;  // fold layer4 1/sqrt(H) + EPS into store

  // layer 4: W4R[fb] contiguous 2560-float run, consumed sequentially.
#pragma unroll 1
  for (int fb = 0; fb < 8; ++fb) {
    const float* base = W4R + fb * 2560;
    float w[5][8];
#pragma unroll
    for (int p = 0; p < 5; ++p)
#pragma unroll
      for (int j = 0; j < 8; ++j) w[p][j] = 0.0f;
#pragma unroll
    for (int k = 0; k < 64; ++k) {
      const float* wr = base + k * 40;  // uniform, contiguous -> wide s_load
      float hk = h3[k];
#pragma unroll
      for (int p = 0; p < 5; ++p)
#pragma unroll
        for (int j = 0; j < 8; ++j) w[p][j] += hk * wr[p * 8 + j];
    }
    float4 s0 = *(const float4*)(srow + fb * 8);
    float4 s1 = *(const float4*)(srow + fb * 8 + 4);
    float4 x0 = *(const float4*)(vrow + fb * 8);
    float4 x1 = *(const float4*)(vrow + fb * 8 + 4);
    float4 y0 = *(const float4*)(vrow + 64 + fb * 8);
    float4 y1 = *(const float4*)(vrow + 64 + fb * 8 + 4);
    float4 z0 = *(const float4*)(vrow + 128 + fb * 8);
    float4 z1 = *(const float4*)(vrow + 128 + fb * 8 + 4);
    float ssv[8] = {s0.x, s0.y, s0.z, s0.w, s1.x, s1.y, s1.z, s1.w};
    float vxv[8] = {x0.x, x0.y, x0.z, x0.w, x1.x, x1.y, x1.z, x1.w};
    float vyv[8] = {y0.x, y0.y, y0.z, y0.w, y1.x, y1.y, y1.z, y1.w};
    float vzv[8] = {z0.x, z0.y, z0.z, z0.w, z1.x, z1.y, z1.z, z1.w};
    float ms[8], mx[8], my[8], mz[8];
#pragma unroll
    for (int j = 0; j < 8; ++j) {
      float vvx = vxv[j], vvy = vyv[j], vvz = vzv[j];
      float dt = vvx * Yx + vvy * Yy + vvz * Yz;
      float cx = vvy * Yz - vvz * Yy;
      float cy = vvz * Yx - vvx * Yz;
      float cz = vvx * Yy - vvy * Yx;
      ms[j] = C * (w[0][j] * ssv[j] + w[3][j] * dt);
      mx[j] = C * (w[1][j] * Yx + w[2][j] * vvx + w[4][j] * (cx * RS2));
      my[j] = C * (w[1][j] * Yy + w[2][j] * vvy + w[4][j] * (cy * RS2));
      mz[j] = C * (w[1][j] * Yz + w[2][j] * vvz + w[4][j] * (cz * RS2));
    }
    uint4 pk;
    pk.x = bfpair(ms[0], ms[1]); pk.y = bfpair(ms[2], ms[3]);
    pk.z = bfpair(ms[4], ms[5]); pk.w = bfpair(ms[6], ms[7]);
    *(uint4*)(mrow + fb * 8) = pk;
    pk.x = bfpair(mx[0], mx[1]); pk.y = bfpair(mx[2], mx[3]);
    pk.z = bfpair(mx[4], mx[5]); pk.w = bfpair(mx[6], mx[7]);
    *(uint4*)(mrow + 64 + fb * 8) = pk;
    pk.x = bfpair(my[0], my[1]); pk.y = bfpair(my[2], my[3]);
    pk.z = bfpair(my[4], my[5]); pk.w = bfpair(my[6], my[7]);
    *(uint4*)(mrow + 128 + fb * 8) = pk;
    pk.x = bfpair(mz[0], mz[1]); pk.y = bfpair(mz[2], mz[3]);
    pk.z = bfpair(mz[4], mz[5]); pk.w = bfpair(mz[6], mz[7]);
    *(uint4*)(mrow + 192 + fb * 8) = pk;
  }
}

// one wave per node; scans its receiver-CSR edges, keeps those whose
// sender-order position lies in this chunk, reads full coalesced rows.
__global__ __launch_bounds__(256) void k_gather(
    const unsigned short* __restrict__ m_buf,
    const int* __restrict__ row_start_r, const int* __restrict__ elist_r,
    const int* __restrict__ pos_s,
    float* __restrict__ acc, int p0, int p1) {
  int g = threadIdx.x & 63;
  int wv = threadIdx.x >> 6;
  int n = blockIdx.x * 4 + wv;
  int beg = row_start_r[n], end = row_start_r[n + 1];
  float4 a = make_float4(0.f, 0.f, 0.f, 0.f);
  bool any = false;
  for (int i = beg; i < end; ++i) {
    int p = pos_s[elist_r[i]];        // wave-uniform
    if (p >= p0 && p < p1) {
      uint2 m = *(const uint2*)(m_buf + (size_t)(p - p0) * 256 + g * 4);
      a.x += lo16(m.x);
      a.y += hi16(m.x);
      a.z += lo16(m.y);
      a.w += hi16(m.y);
      any = true;
    }
  }
  if (!any) return;
  float* dst = acc + (size_t)n * 256 + g * 4;
  float4 p = *(const float4*)dst;  // serialized chunks: RMW is safe
  *(float4*)dst = make_float4(a.x + p.x, a.y + p.y, a.z + p.z, a.w + p.w);
}

__global__ __launch_bounds__(256) void k_post(
    const float* __restrict__ nf, const float* __restrict__ acc,
    const float* __restrict__ Wdns, const float* __restrict__ Wdnv,
    const float* __restrict__ Wsks, const float* __restrict__ Wskv,
    const float* __restrict__ Wsc,
    const float* __restrict__ Wpss, const float* __restrict__ Wpsv,
    const float* __restrict__ Wout, const int* __restrict__ species,
    float* __restrict__ out) {
  __shared__ __align__(16) float xch[4][4][4][68];
  int g = threadIdx.x & 63;
  int wv = threadIdx.x >> 6;
  int n0 = (blockIdx.x * 4 + wv) * 4;
  int spec[4];
#pragma unroll
  for (int i = 0; i < 4; ++i) spec[i] = species[n0 + i];
  float s3[4] = {0, 0, 0, 0};
  float v3[4][3] = {{0,0,0},{0,0,0},{0,0,0},{0,0,0}};
  float sks[4] = {0, 0, 0, 0};
  float skv[4][3] = {{0,0,0},{0,0,0},{0,0,0},{0,0,0}};
  for (int fq = 0; fq < 16; ++fq) {
    int f = fq * 4;
    float d0 = Wdns[(f + 0) * 64 + g], d1 = Wdns[(f + 1) * 64 + g];
    float d2 = Wdns[(f + 2) * 64 + g], d3 = Wdns[(f + 3) * 64 + g];
    float e0 = Wdnv[(f + 0) * 64 + g], e1 = Wdnv[(f + 1) * 64 + g];
    float e2 = Wdnv[(f + 2) * 64 + g], e3 = Wdnv[(f + 3) * 64 + g];
#pragma unroll
    for (int i = 0; i < 4; ++i) {
      int n = n0 + i;
      const float* arow = acc + (size_t)n * 256;
      float4 sa = *(const float4*)(arow + f);
      float4 vx = *(const float4*)(arow + 64 + f);
      float4 vy = *(const float4*)(arow + 128 + f);
      float4 vz = *(const float4*)(arow + 192 + f);
      s3[i]    += sa.x * d0 + sa.y * d1 + sa.z * d2 + sa.w * d3;
      v3[i][0] += vx.x * e0 + vx.y * e1 + vx.z * e2 + vx.w * e3;
      v3[i][1] += vy.x * e0 + vy.y * e1 + vy.z * e2 + vy.w * e3;
      v3[i][2] += vz.x * e0 + vz.y * e1 + vz.z * e2 + vz.w * e3;
      const float* ksb = Wsks + spec[i] * 4096 + f * 64 + g;
      const float* kvb = Wskv + spec[i] * 4096 + f * 64 + g;
      float k0 = ksb[0], k1 = ksb[64], k2 = ksb[128], k3 = ksb[192];
      float q0 = kvb[0], q1 = kvb[64], q2 = kvb[128], q3 = kvb[192];
      const float* row = nf + (size_t)n * 256;
      float4 s04 = *(const float4*)(row + f);
      const float4* vr = (const float4*)(row + 64 + fq * 12);
      float4 va = vr[0], vb = vr[1], vc = vr[2];
      sks[i]    += s04.x * k0 + s04.y * k1 + s04.z * k2 + s04.w * k3;
      skv[i][0] += va.x * q0 + va.w * q1 + vb.z * q2 + vc.y * q3;
      skv[i][1] += va.y * q0 + vb.x * q1 + vb.w * q2 + vc.z * q3;
      skv[i][2] += va.z * q0 + vb.y * q1 + vc.x * q2 + vc.w * q3;
    }
  }
#pragma unroll
  for (int i = 0; i < 4; ++i) {
    float s = s3[i] * INV8;
    float vx = v3[i][0] * INV8, vy = v3[i][1] * INV8, vz = v3[i][2] * INV8;
    float vn2 = vx * vx + vy * vy + vz * vz;
    const float* wz = Wsc + spec[i] * 576 + g;
    float w0 = wz[0], w1 = wz[64], w2 = wz[128], w3 = wz[192], w4 = wz[256];
    float w5 = wz[320], w6 = wz[384], w7 = wz[448], w8 = wz[512];
    float s_o = w0 * s + w1 * s * s + w2 * vn2 + w3 * s * s * s + w4 * s * vn2;
    float vcm = w5 + w6 * s + w7 * s * s + w8 * vn2;
    xch[wv][i][0][g] = s_o;
    xch[wv][i][1][g] = vcm * vx;
    xch[wv][i][2][g] = vcm * vy;
    xch[wv][i][3][g] = vcm * vz;
  }
  __syncthreads();
  float s4[4] = {0, 0, 0, 0};
  float v4[4][3] = {{0,0,0},{0,0,0},{0,0,0},{0,0,0}};
  for (int fq = 0; fq < 16; ++fq) {
    int f = fq * 4;
    float p0 = Wpss[(f + 0) * 64 + g], p1 = Wpss[(f + 1) * 64 + g];
    float p2 = Wpss[(f + 2) * 64 + g], p3 = Wpss[(f + 3) * 64 + g];
    float q0 = Wpsv[(f + 0) * 64 + g], q1 = Wpsv[(f + 1) * 64 + g];
    float q2 = Wpsv[(f + 2) * 64 + g], q3 = Wpsv[(f + 3) * 64 + g];
#pragma unroll
    for (int i = 0; i < 4; ++i) {
      float4 so = *(const float4*)(&xch[wv][i][0][f]);
      float4 u0 = *(const float4*)(&xch[wv][i][1][f]);
      float4 u1 = *(const float4*)(&xch[wv][i][2][f]);
      float4 u2 = *(const float4*)(&xch[wv][i][3][f]);
      s4[i]    += so.x * p0 + so.y * p1 + so.z * p2 + so.w * p3;
      v4[i][0] += u0.x * q0 + u0.y * q1 + u0.z * q2 + u0.w * q3;
      v4[i][1] += u1.x * q0 + u1.y * q1 + u1.z * q2 + u1.w * q3;
      v4[i][2] += u2.x * q0 + u2.y * q1 + u2.z * q2 + u2.w * q3;
    }
  }
  float wo = Wout[g];
#pragma unroll
  for (int i = 0; i < 4; ++i) {
    int n = n0 + i;
    float sf = s4[i] * INV8 + sks[i] * INVZ;
    float fx = v4[i][0] * INV8 + skv[i][0] * INVZ;
    float fy = v4[i][1] * INV8 + skv[i][1] * INVZ;
    float fz = v4[i][2] * INV8 + skv[i][2] * INVZ;
    float* orow = out + NN + (size_t)n * 256;
    orow[g] = sf;
    orow[64 + g * 3 + 0] = fx;
    orow[64 + g * 3 + 1] = fy;
    orow[64 + g * 3 + 2] = fz;
    float tsum = sf * wo;
#pragma unroll
    for (int off = 32; off > 0; off >>= 1) tsum += __shfl_down(tsum, off);
    if (g == 0) out[n] = tsum * INV8;
  }
}

extern "C" void kernel_launch(void* const* d_in, const int* in_sizes, int n_in,
                              void* d_out, int out_size, void* d_ws, size_t ws_size,
                              hipStream_t stream) {
  (void)in_sizes; (void)n_in; (void)out_size; (void)ws_size;
  const float* vecs = (const float*)d_in[0];
  const float* nf   = (const float*)d_in[1];
  const float* re   = (const float*)d_in[2];
  const float* Wsks = (const float*)d_in[3];
  const float* Wskv = (const float*)d_in[4];
  const float* Wups = (const float*)d_in[5];
  const float* Wupv = (const float*)d_in[6];
  const float* W1   = (const float*)d_in[7];
  const float* W2   = (const float*)d_in[8];
  const float* W3   = (const float*)d_in[9];
  const float* W4   = (const float*)d_in[10];
  const float* Wdns = (const float*)d_in[11];
  const float* Wdnv = (const float*)d_in[12];
  const float* Wsc  = (const float*)d_in[13];
  const float* Wpss = (const float*)d_in[14];
  const float* Wpsv = (const float*)d_in[15];
  const float* Wout = (const float*)d_in[16];
  const int* species = (const int*)d_in[17];
  const int* snd     = (const int*)d_in[18];
  const int* rcv     = (const int*)d_in[19];

  float* ws = (float*)d_ws;
  float* s_up    = ws;                         // [0, 2097152)
  float* v_up    = ws + 2097152;               // [2097152, 8388608)
  float* acc     = ws + 8388608;               // [8388608, 16777216)
  float* wT      = ws + 16777216;              // 25088
  int* row_st_r  = (int*)(ws + 16802304);      // 32772
  int* row_st_s  = (int*)(ws + 16835076);      // 32772
  int* cursor_r  = (int*)(ws + 16867848);      // 32768
  int* cursor_s  = (int*)(ws + 16900616);      // 32768
  int* elist_r   = (int*)(ws + 16933384);      // 262144
  int* selist    = (int*)(ws + 17195528);      // 262144
  int* pos_s     = (int*)(ws + 17457672);      // 262144
  unsigned short* m_buf = (unsigned short*)(ws + 17719816);  // EC*256 bf16

  float* W1T = wT;
  float* W3T = wT + 512;
  float* W4R = wT + 4608;

  hipMemsetAsync(cursor_r, 0, 2 * NN * sizeof(int), stream);  // r + s contiguous
  hipMemsetAsync(acc, 0, (size_t)NN * 256 * sizeof(float), stream);
  k_wt<<<98, 256, 0, stream>>>(W1, W3, W4, wT);
  k_hist<<<EE / 256, 256, 0, stream>>>(rcv, cursor_r);
  k_hist<<<EE / 256, 256, 0, stream>>>(snd, cursor_s);
  k_scan<<<1, 1024, 0, stream>>>(cursor_r, row_st_r, cursor_r);
  k_scan<<<1, 1024, 0, stream>>>(cursor_s, row_st_s, cursor_s);
  k_fill<<<EE / 256, 256, 0, stream>>>(rcv, cursor_r, elist_r);
  k_fill_pos<<<EE / 256, 256, 0, stream>>>(snd, cursor_s, selist, pos_s);
  k_up<<<2048, 256, 0, stream>>>(nf, Wups, Wupv, s_up, v_up);
  for (int c = 0; c < 2; ++c) {
    k_edge<<<EC / 128, 128, 0, stream>>>(vecs, re, W1T, W2, W3T, W4R,
                                         s_up, v_up, snd, selist,
                                         c * EC, m_buf);
    k_gather<<<NN / 4, 256, 0, stream>>>(m_buf, row_st_r, elist_r, pos_s,
                                         acc, c * EC, (c + 1) * EC);
  }
  k_post<<<2048, 256, 0, stream>>>(nf, acc, Wdns, Wdnv, Wsks, Wskv, Wsc,
                                   Wpss, Wpsv, Wout, species, (float*)d_out);
}